// Round 2
// baseline (415.500 us; speedup 1.0000x reference)
//
#include <hip/hip_runtime.h>
#include <math.h>

#define ZD 64     // output channels
#define IC 256    // input channels

// ---------------- degree histogram (in-degree by dst, excl. self-loop) ----
__global__ void k_deg(const int* __restrict__ dst, int E, unsigned* __restrict__ deg) {
    int i = blockIdx.x * blockDim.x + threadIdx.x;
    if (i < E) atomicAdd(&deg[dst[i]], 1u);
}

// ---------------- linear + L2-normalize*1.8 + self-loop term --------------
// W^T staged in LDS as float4 groups: wt4[g][c] = {W[c][4g..4g+3]}
__global__ __launch_bounds__(256) void k_linnorm(
    const float* __restrict__ x, const float* __restrict__ W,
    const float* __restrict__ b, const unsigned* __restrict__ deg,
    float* __restrict__ h, float* __restrict__ out, int N) {
    __shared__ float4 wt4[IC / 4][ZD];  // exactly 64 KiB

    // Cooperative stage: iterate in LDS-linear order -> conflict-free ds_writes,
    // scattered-but-L2-cached global reads of the 64KB W.
    for (int o = threadIdx.x; o < ZD * IC; o += blockDim.x) {
        int comp = o & 3;
        int c    = (o >> 2) & (ZD - 1);
        int g    = o >> 8;
        ((float*)wt4)[o] = W[c * IC + g * 4 + comp];
    }
    int lane = threadIdx.x & 63;
    float bias = b[lane];
    __syncthreads();

    int wid = blockIdx.x * (blockDim.x >> 6) + (threadIdx.x >> 6);
    int nw  = gridDim.x * (blockDim.x >> 6);
    for (int row = wid; row < N; row += nw) {
        const float4* xr = (const float4*)(x + (size_t)row * IC);
        float acc = 0.f;
#pragma unroll 8
        for (int g = 0; g < IC / 4; ++g) {
            float4 xv = xr[g];          // uniform across wave (broadcast load)
            float4 wv = wt4[g][lane];   // ds_read_b128, conflict-free
            acc += xv.x * wv.x + xv.y * wv.y + xv.z * wv.z + xv.w * wv.w;
        }
        acc += bias;

        // wave-wide sum of squares (64-lane butterfly)
        float ss = acc * acc;
#pragma unroll
        for (int o = 32; o; o >>= 1) ss += __shfl_xor(ss, o, 64);

        float scale = 1.8f / fmaxf(sqrtf(ss), 1e-12f);
        float hv = acc * scale;
        size_t idx = (size_t)row * ZD + lane;
        h[idx] = hv;
        // self-loop contribution: coef = dinv[i]^2 = 1/(deg_in+1); also
        // fully initializes d_out (harness poisons it before every launch)
        float dp = (float)(deg[row] + 1u);
        out[idx] = hv / dp;
    }
}

// ---------------- edge scatter: out[d] += dinv[s]*dinv[d]*h[s] ------------
__global__ __launch_bounds__(256) void k_edge(
    const int* __restrict__ src, const int* __restrict__ dst,
    const unsigned* __restrict__ deg, const float* __restrict__ h,
    float* __restrict__ out, int E) {
    int e = (blockIdx.x * blockDim.x + threadIdx.x) >> 6;
    if (e >= E) return;
    int lane = threadIdx.x & 63;
    int s = src[e];
    int d = dst[e];
    float ds = (float)(deg[s] + 1u);
    float dd = (float)(deg[d] + 1u);
    float coef = rsqrtf(ds * dd);
    float v = h[(size_t)s * ZD + lane] * coef;
    atomicAdd(&out[(size_t)d * ZD + lane], v);
}

extern "C" void kernel_launch(void* const* d_in, const int* in_sizes, int n_in,
                              void* d_out, int out_size, void* d_ws, size_t ws_size,
                              hipStream_t stream) {
    const float* x = (const float*)d_in[0];
    const float* W = (const float*)d_in[1];
    const float* b = (const float*)d_in[2];
    const int* edge_index = (const int*)d_in[3];

    const int N = in_sizes[0] / IC;       // 50000
    const int E = in_sizes[3] / 2;        // 800000
    const int* src = edge_index;
    const int* dst = edge_index + E;

    float* out = (float*)d_out;

    // workspace layout: h [N*ZD f32] | deg [N u32]
    float* h = (float*)d_ws;
    unsigned* deg = (unsigned*)((char*)d_ws + (size_t)N * ZD * sizeof(float));

    hipMemsetAsync(deg, 0, (size_t)N * sizeof(unsigned), stream);

    k_deg<<<(E + 255) / 256, 256, 0, stream>>>(dst, E, deg);

    // 512 blocks: 2 blocks/CU at 64KB LDS each; W staged 512x (32MB L2 traffic)
    k_linnorm<<<512, 256, 0, stream>>>(x, W, b, deg, h, out, N);

    // one wave per edge
    k_edge<<<(E + 3) / 4, 256, 0, stream>>>(src, dst, deg, h, out, E);
}